// Round 4
// baseline (4166.620 us; speedup 1.0000x reference)
//
#include <hip/hip_runtime.h>

// Round 6: A-in-registers. gru_fused keeps only WEIGHTS in LDS (2 x 20 KB =
// 40 KB -> exactly 4 blocks/CU, 16 waves/CU); input/hidden A-fragments are
// loaded per-lane straight from global (bf16x8 at row*1024 + k0 + quad*8),
// double-buffered in registers across tiles. ds_read/wave/tile 18 -> 10, so
// the LDS pipe (was ~1920 cyc/CU-window vs MFMA 1552) drops to ~1600 vs 3104:
// MFMA-bound with headroom, and 4 independent blocks desync the barriers.
// One counted vmcnt(13)/tile (W(t)5+A(t)8 drained, W(t+1)5+A(t+1)8 in
// flight), 2 barriers/tile, slot-XOR swizzle on B, setprio around MFMA.
// R5's phase-split REVERTED (290 us > R3's 270: 7 barriers/tile at 1 block/CU
// with unchanged pipe balance). convert_bf16: R0 one-shot form.

#define BM 128
#define BN 64
#define BK 32

typedef __attribute__((ext_vector_type(8))) short          bf16x8;
typedef __attribute__((ext_vector_type(8))) unsigned short u16x8;
typedef __attribute__((ext_vector_type(4))) float          f32x4;

__device__ __forceinline__ unsigned short f2bf(float f) {
    union { float f; unsigned u; } v; v.f = f;
    unsigned r = v.u + 0x7FFFu + ((v.u >> 16) & 1u);  // RNE
    return (unsigned short)(r >> 16);
}

// ---- Pass 1: fp32 -> bf16 conversion into ws (one vec8 per thread) ----
// ws layout (elements): [0) input 16777216 | [16777216) hidden 16777216 |
//                       [33554432 + g*1048576) W_g for g=0..4
// Total vec8 = 4,849,664 = 18944 blocks * 256.
__global__ __launch_bounds__(256) void convert_bf16(
    const float* __restrict__ in0, const float* __restrict__ in1,
    const float* __restrict__ w0, const float* __restrict__ w1,
    const float* __restrict__ w2, const float* __restrict__ w3,
    const float* __restrict__ w4, unsigned short* __restrict__ ws)
{
    const long long e = ((long long)blockIdx.x * 256 + threadIdx.x) * 8;
    const float* src;
    if (e < 16777216LL) {
        src = in0 + e;
    } else if (e < 33554432LL) {
        src = in1 + (e - 16777216LL);
    } else {
        const long long t = e - 33554432LL;
        const int g = (int)(t >> 20);
        const long long within = t & 1048575LL;
        const float* w = (g == 0) ? w0 : (g == 1) ? w1 : (g == 2) ? w2 : (g == 3) ? w3 : w4;
        src = w + within;
    }
    const float4 a = *reinterpret_cast<const float4*>(src);
    const float4 b = *reinterpret_cast<const float4*>(src + 4);
    u16x8 o;
    o[0] = f2bf(a.x); o[1] = f2bf(a.y); o[2] = f2bf(a.z); o[3] = f2bf(a.w);
    o[4] = f2bf(b.x); o[5] = f2bf(b.y); o[6] = f2bf(b.z); o[7] = f2bf(b.w);
    *reinterpret_cast<u16x8*>(ws + e) = o;
}

// ---- async 16B global->LDS ----
__device__ __forceinline__ void async16(const void* g, void* l) {
    __builtin_amdgcn_global_load_lds(
        (const __attribute__((address_space(1))) unsigned int*)g,
        (__attribute__((address_space(3))) unsigned int*)l, 16, 0, 0);
}

#define CFENCE() asm volatile("" ::: "memory")
#define MFMA16(a, b, c) __builtin_amdgcn_mfma_f32_16x16x32_bf16((a), (b), (c), 0, 0, 0)

// ---- Pass 2: fused GRU ----
// LDS per buffer: sW[5][64 rows][64 B] = 20480 B. Slot swizzle: logical 16B
// slot c of row n stored at physical c ^ ((n>>1)&3) (applied to the GLOBAL
// source at staging; same involution on reads -> conflict-free, measured 0).
// 1280 slots = 256 threads x 5.
// Waves 2Mx2N: wave (wm,wn) owns rows [wm*64,+64) x cols [wn*32,+32).
__global__ __launch_bounds__(256, 4) void gru_fused(
    const unsigned short* __restrict__ bf,   // ws: bf16 image
    const float* __restrict__ hidden,        // fp32, for epilogue z*h
    const float* __restrict__ b_ri, const float* __restrict__ b_rh,
    const float* __restrict__ b_zi, const float* __restrict__ b_ni,
    const float* __restrict__ b_nh,
    float* __restrict__ out)
{
    const int H = 1024, K = 1024;
    const int BH = 16384 * 1024;

    __shared__ __align__(16) unsigned char sW[2][20480];   // 40960 B total -> 4 blocks/CU

    const int tid  = threadIdx.x;
    const int wave = tid >> 6;
    const int lane = tid & 63;
    const int quad = lane >> 4;
    const int l16  = lane & 15;
    const int sq   = quad ^ ((l16 >> 1) & 3);   // swizzled 16B slot for B reads
    const int wm   = wave >> 1;                 // 0..1 (M position)
    const int wn   = wave & 1;                  // 0..1 (N position)

    const int row0 = blockIdx.y * BM;
    const int col0 = blockIdx.x * BN;

    const unsigned short* inB  = bf;               // input  bf16 [16384][1024]
    const unsigned short* hidB = bf + 16777216;    // hidden bf16 [16384][1024]

    // Weight staging: slot s = j*256 + tid, j=0..4. g = s>>8; within-gate
    // tt = s&255: n = tt>>2 (col row), physical slot p = tt&3 holds logical
    // column p ^ ((n>>1)&3).
    unsigned srcoff[5];
    #pragma unroll
    for (int j = 0; j < 5; ++j) {
        const int s = j * 256 + tid;
        const int g = s >> 8;
        const int tt = s & 255;
        const int n = tt >> 2;
        const int c = (tt & 3) ^ ((n >> 1) & 3);
        srcoff[j] = 33554432u + (unsigned)g * 1048576u + (unsigned)(col0 + n) * 1024u + (unsigned)c * 8u;
    }

    // A-fragment global base pointers (k0=0): lane reads 16B at
    // row*1024 + k0 + quad*8 (elements). 16B-aligned since k0 % 32 == 0.
    const unsigned short* pIn[4];
    const unsigned short* pHid[4];
    #pragma unroll
    for (int mi = 0; mi < 4; ++mi) {
        const int r = row0 + wm * 64 + mi * 16 + l16;
        pIn [mi] = inB  + (unsigned)r * 1024u + (unsigned)quad * 8u;
        pHid[mi] = hidB + (unsigned)r * 1024u + (unsigned)quad * 8u;
    }

    #define STAGEW(k0, dst) do {                                               \
        _Pragma("unroll")                                                      \
        for (int j = 0; j < 5; ++j)                                            \
            async16(bf + srcoff[j] + (unsigned)(k0), (dst) + (j * 256 + tid) * 16); \
    } while (0)

    bf16x8 aIn[2][4], aHid[2][4];   // double-buffered A fragments (static idx only)
    #define LOADA(set, k0) do {                                                \
        _Pragma("unroll")                                                      \
        for (int mi = 0; mi < 4; ++mi) {                                       \
            aIn [set][mi] = *reinterpret_cast<const bf16x8*>(pIn [mi] + (k0)); \
            aHid[set][mi] = *reinterpret_cast<const bf16x8*>(pHid[mi] + (k0)); \
        }                                                                      \
    } while (0)

    f32x4 acc[5][4][2];
    #pragma unroll
    for (int g = 0; g < 5; ++g)
        #pragma unroll
        for (int mi = 0; mi < 4; ++mi)
            #pragma unroll
            for (int ni = 0; ni < 2; ++ni)
                acc[g][mi][ni] = (f32x4){0.f, 0.f, 0.f, 0.f};

    #define COMPUTE(set, sbuf) do {                                            \
        __builtin_amdgcn_s_setprio(1);                                         \
        _Pragma("unroll")                                                      \
        for (int g = 0; g < 5; ++g) {                                          \
            _Pragma("unroll")                                                  \
            for (int ni = 0; ni < 2; ++ni) {                                   \
                const int n = wn * 32 + ni * 16 + l16;                         \
                const bf16x8 bb = *reinterpret_cast<const bf16x8*>(            \
                    (sbuf) + g * 4096 + n * 64 + sq * 16);                     \
                _Pragma("unroll")                                              \
                for (int mi = 0; mi < 4; ++mi) {                               \
                    acc[g][mi][ni] = MFMA16(                                   \
                        (g == 1 || g == 4) ? aHid[set][mi] : aIn[set][mi],     \
                        bb, acc[g][mi][ni]);                                   \
                }                                                              \
            }                                                                  \
        }                                                                      \
        __builtin_amdgcn_s_setprio(0);                                         \
    } while (0)

    #define TILE_WAIT(n) do {                                                  \
        asm volatile("s_waitcnt vmcnt(" #n ")" ::: "memory");                  \
        __builtin_amdgcn_sched_barrier(0);                                     \
        __builtin_amdgcn_s_barrier(); CFENCE();                                \
    } while (0)

    // ---- prologue: queue = [W0:5, A0:8, W1:5, A1:8] ----
    STAGEW(0, sW[0]);            CFENCE();
    LOADA(0, 0);                 CFENCE();
    STAGEW(BK, sW[1]);           CFENCE();
    LOADA(1, BK);                CFENCE();

    // Steady tile t: vmcnt(13) drains W(t)+A(t), leaves W(t+1):5 + A(t+1):8.
    // After compute + barrier, restage W(t+2) into the buffer just consumed
    // and issue A(t+2) into the register set just consumed.
    #pragma unroll 1
    for (int i = 0; i < 15; ++i) {        // tiles 0..29
        const int t = 2 * i;
        TILE_WAIT(13);
        COMPUTE(0, sW[0]);
        CFENCE(); __builtin_amdgcn_s_barrier(); CFENCE();
        STAGEW((t + 2) * BK, sW[0]);  CFENCE();
        LOADA(0, (t + 2) * BK);       CFENCE();

        TILE_WAIT(13);
        COMPUTE(1, sW[1]);
        CFENCE(); __builtin_amdgcn_s_barrier(); CFENCE();
        STAGEW((t + 3) * BK, sW[1]);  CFENCE();
        LOADA(1, (t + 3) * BK);       CFENCE();
    }
    // tile 30: queue [W30:5, A30:8, W31:5, A31:8] -> vmcnt(13)
    TILE_WAIT(13);
    COMPUTE(0, sW[0]);
    CFENCE();
    // tile 31: drain everything
    TILE_WAIT(0);
    COMPUTE(1, sW[1]);

    // Epilogue: C/D layout row = quad*4 + r4, col = l16 per 16x16 tile.
    #pragma unroll
    for (int ni = 0; ni < 2; ++ni) {
        const int gcol = col0 + wn * 32 + ni * 16 + l16;
        const float bri = b_ri[gcol], brh = b_rh[gcol], bzi = b_zi[gcol];
        const float bni = b_ni[gcol], bnh = b_nh[gcol];
        #pragma unroll
        for (int mi = 0; mi < 4; ++mi) {
            #pragma unroll
            for (int r4 = 0; r4 < 4; ++r4) {
                const int grow = row0 + wm * 64 + mi * 16 + quad * 4 + r4;
                const float g_ri = acc[0][mi][ni][r4];
                const float g_rh = acc[1][mi][ni][r4];
                const float g_zi = acc[2][mi][ni][r4];
                const float g_ni = acc[3][mi][ni][r4];
                const float g_nh = acc[4][mi][ni][r4];
                const float rh = g_rh + brh;                  // shared by r and z (reference bug kept)
                const float rr = 1.f / (1.f + __expf(-(g_ri + bri + rh)));
                const float zz = 1.f / (1.f + __expf(-(g_zi + bzi + rh)));
                const float nn = tanhf(g_ni + bni + rr * (g_nh + bnh));
                const float h  = hidden[(long long)grow * H + gcol];
                const float o  = (1.f - zz) * nn + zz * h;
                out[(long long)grow * H + gcol]      = o;
                out[BH + (long long)grow * H + gcol] = o;
            }
        }
    }
}

extern "C" void kernel_launch(void* const* d_in, const int* in_sizes, int n_in,
                              void* d_out, int out_size, void* d_ws, size_t ws_size,
                              hipStream_t stream) {
    const float* input  = (const float*)d_in[0];
    const float* hidden = (const float*)d_in[1];
    const float* W_ri = (const float*)d_in[2];
    const float* b_ri = (const float*)d_in[3];
    const float* W_rh = (const float*)d_in[4];
    const float* b_rh = (const float*)d_in[5];
    const float* W_zi = (const float*)d_in[6];
    const float* b_zi = (const float*)d_in[7];
    // d_in[8], d_in[9] = W_z_h, b_z_h: dead per the reference's bug (z uses r_h)
    const float* W_ni = (const float*)d_in[10];
    const float* b_ni = (const float*)d_in[11];
    const float* W_nh = (const float*)d_in[12];
    const float* b_nh = (const float*)d_in[13];
    float* out = (float*)d_out;
    unsigned short* ws = (unsigned short*)d_ws;

    // gate order in ws: 0=r_i 1=r_h 2=z_i 3=n_i 4=n_h
    convert_bf16<<<18944, 256, 0, stream>>>(input, hidden, W_ri, W_rh, W_zi, W_ni, W_nh, ws);

    dim3 grid(1024 / BN, 16384 / BM);  // (16, 128)
    gru_fused<<<grid, 256, 0, stream>>>(ws, hidden, b_ri, b_rh, b_zi, b_ni, b_nh, out);
}

// Round 5
// 1479.518 us; speedup vs baseline: 2.8162x; 2.8162x over previous
//
#include <hip/hip_runtime.h>

// Round 7: single-kernel fusion. The fp32->bf16 convert pass is eliminated;
// gru_fused reads fp32 input/hidden/weights directly, converts in-register
// (f2bf RNE, hidden under MFMA on the VALU pipe), and stages bf16 tiles into
// LDS via ds_write_b128 (T14 reg-staging: 18 global_load_dwordx4 for tile t+1
// issued BEFORE compute(t); vmcnt lands under the MFMA cluster). One barrier
// per tile (reads(t) hit buf[t&1], writes(t+1) hit buf[~t&1] -> single
// end-of-tile barrier covers both cross-wave hazards). Wave layout 2Mx2N,
// slot-XOR swizzle kept on the LDS image (conflicts measured 0), setprio
// around MFMA. __launch_bounds__(256,2): unified reg cap 512 >= ~310 needed
// (R4's (256,4) capped at ~256 and spilled the 160-reg accumulator -> 4 ms).

#define BM 128
#define BN 64
#define BK 32

typedef __attribute__((ext_vector_type(8))) short          bf16x8;
typedef __attribute__((ext_vector_type(8))) unsigned short u16x8;
typedef __attribute__((ext_vector_type(4))) float          f32x4;

__device__ __forceinline__ unsigned short f2bf(float f) {
    union { float f; unsigned u; } v; v.f = f;
    unsigned r = v.u + 0x7FFFu + ((v.u >> 16) & 1u);  // RNE
    return (unsigned short)(r >> 16);
}

#define CFENCE() asm volatile("" ::: "memory")
#define MFMA16(a, b, c) __builtin_amdgcn_mfma_f32_16x16x32_bf16((a), (b), (c), 0, 0, 0)

// LDS image per buffer (bf16, 36864 B):
//   [0, 8192)       sIn  [128 rows][64 B]   (4 x 16B slots per row)
//   [8192, 16384)   sHid [128 rows][64 B]
//   [16384, 36864)  sW[5][64 rows][64 B]
// Slot swizzle: physical 16B slot p of row r holds logical column
// c = p ^ ((r>>1)&3) (same involution applied on reads via sq).
// 2304 slots = 256 threads x 9; thread's slot j: s = (j*4+wave)*64 + lane.
__global__ __launch_bounds__(256, 2) void gru_fused(
    const float* __restrict__ input,         // fp32 [16384][1024]
    const float* __restrict__ hidden,        // fp32 [16384][1024]
    const float* __restrict__ Wri, const float* __restrict__ Wrh,
    const float* __restrict__ Wzi, const float* __restrict__ Wni,
    const float* __restrict__ Wnh,
    const float* __restrict__ b_ri, const float* __restrict__ b_rh,
    const float* __restrict__ b_zi, const float* __restrict__ b_ni,
    const float* __restrict__ b_nh,
    float* __restrict__ out)
{
    const int H = 1024, K = 1024;
    const int BH = 16384 * 1024;

    __shared__ __align__(16) unsigned char sBuf[2][36864];

    const int tid  = threadIdx.x;
    const int wave = tid >> 6;
    const int lane = tid & 63;
    const int quad = lane >> 4;
    const int l16  = lane & 15;
    const int sq   = quad ^ ((l16 >> 1) & 3);   // swizzled 16B slot for reads
    const int wm   = wave >> 1;                 // 0..1 (M position)
    const int wn   = wave & 1;                  // 0..1 (N position)

    const int row0 = blockIdx.y * BM;
    const int col0 = blockIdx.x * BN;

    // Per-slot fp32 source pointers (at k=0) and LDS byte offsets.
    const float* srcp[9];
    int ldsoff[9];
    #pragma unroll
    for (int j = 0; j < 9; ++j) {
        const int s = (j * 4 + wave) * 64 + lane;
        ldsoff[j] = s * 16;
        if (s < 512) {                       // input tile: 4 slots per row
            const int r = s >> 2;
            const int c = (s & 3) ^ ((r >> 1) & 3);
            srcp[j] = input + (long long)(row0 + r) * K + c * 8;
        } else if (s < 1024) {               // hidden tile
            const int r = (s - 512) >> 2;
            const int c = ((s - 512) & 3) ^ ((r >> 1) & 3);
            srcp[j] = hidden + (long long)(row0 + r) * K + c * 8;
        } else {                             // weight tiles
            const int t = s - 1024;
            const int g = t >> 8;
            const int tt = t & 255;
            const int n = tt >> 2;
            const int c = (tt & 3) ^ ((n >> 1) & 3);
            const float* w = (g == 0) ? Wri : (g == 1) ? Wrh : (g == 2) ? Wzi
                           : (g == 3) ? Wni : Wnh;
            srcp[j] = w + (long long)(col0 + n) * K + c * 8;
        }
    }

    // Raw fp32 staging registers (single set; static indexing only).
    float4 rA[9], rB[9];

    #define LOADRAW(k0) do {                                                   \
        _Pragma("unroll")                                                      \
        for (int j = 0; j < 9; ++j) {                                          \
            rA[j] = *reinterpret_cast<const float4*>(srcp[j] + (k0));          \
            rB[j] = *reinterpret_cast<const float4*>(srcp[j] + (k0) + 4);      \
        }                                                                      \
    } while (0)

    #define CVTWRITE(dst) do {                                                 \
        _Pragma("unroll")                                                      \
        for (int j = 0; j < 9; ++j) {                                          \
            u16x8 o;                                                           \
            o[0] = f2bf(rA[j].x); o[1] = f2bf(rA[j].y);                        \
            o[2] = f2bf(rA[j].z); o[3] = f2bf(rA[j].w);                        \
            o[4] = f2bf(rB[j].x); o[5] = f2bf(rB[j].y);                        \
            o[6] = f2bf(rB[j].z); o[7] = f2bf(rB[j].w);                        \
            *reinterpret_cast<u16x8*>((dst) + ldsoff[j]) = o;                  \
        }                                                                      \
    } while (0)

    f32x4 acc[5][4][2];
    #pragma unroll
    for (int g = 0; g < 5; ++g)
        #pragma unroll
        for (int mi = 0; mi < 4; ++mi)
            #pragma unroll
            for (int ni = 0; ni < 2; ++ni)
                acc[g][mi][ni] = (f32x4){0.f, 0.f, 0.f, 0.f};

    #define COMPUTE(sb) do {                                                   \
        bf16x8 aIn[4], aHid[4];                                                \
        _Pragma("unroll")                                                      \
        for (int mi = 0; mi < 4; ++mi) {                                       \
            const int r = wm * 64 + mi * 16 + l16;                             \
            aIn [mi] = *reinterpret_cast<const bf16x8*>((sb) + r * 64 + sq * 16);          \
            aHid[mi] = *reinterpret_cast<const bf16x8*>((sb) + 8192 + r * 64 + sq * 16);   \
        }                                                                      \
        __builtin_amdgcn_s_setprio(1);                                         \
        _Pragma("unroll")                                                      \
        for (int g = 0; g < 5; ++g) {                                          \
            _Pragma("unroll")                                                  \
            for (int ni = 0; ni < 2; ++ni) {                                   \
                const int n = wn * 32 + ni * 16 + l16;                         \
                const bf16x8 bb = *reinterpret_cast<const bf16x8*>(            \
                    (sb) + 16384 + g * 4096 + n * 64 + sq * 16);               \
                _Pragma("unroll")                                              \
                for (int mi = 0; mi < 4; ++mi) {                               \
                    acc[g][mi][ni] = MFMA16(                                   \
                        (g == 1 || g == 4) ? aHid[mi] : aIn[mi],               \
                        bb, acc[g][mi][ni]);                                   \
                }                                                              \
            }                                                                  \
        }                                                                      \
        __builtin_amdgcn_s_setprio(0);                                         \
    } while (0)

    unsigned char* bufA = &sBuf[0][0];
    unsigned char* bufB = &sBuf[1][0];

    // ---- prologue: tile 0 into bufA ----
    LOADRAW(0);
    CVTWRITE(bufA);
    asm volatile("s_waitcnt lgkmcnt(0)" ::: "memory");
    CFENCE(); __builtin_amdgcn_s_barrier(); CFENCE();

    // ---- main loop: tile t reads buf[t&1]; writes t+1 into buf[~t&1] ----
    // One barrier/tile: write(t+1)->barrier->read(t+1) and
    // read(t-1)->barrier(t-1)->write(t+1 into same buffer) are both covered.
    #pragma unroll 1
    for (int t = 0; t < 32; ++t) {
        const unsigned char* sb = (t & 1) ? bufB : bufA;
        unsigned char*       wb = (t & 1) ? bufA : bufB;
        if (t < 31) LOADRAW((t + 1) * BK);   // fp32 loads fly under compute
        COMPUTE(sb);
        if (t < 31) {
            CVTWRITE(wb);                    // compiler inserts vmcnt for rA/rB
            asm volatile("s_waitcnt lgkmcnt(0)" ::: "memory");
            CFENCE(); __builtin_amdgcn_s_barrier(); CFENCE();
        }
    }

    // Epilogue: C/D layout row = quad*4 + r4, col = l16 per 16x16 tile.
    #pragma unroll
    for (int ni = 0; ni < 2; ++ni) {
        const int gcol = col0 + wn * 32 + ni * 16 + l16;
        const float bri = b_ri[gcol], brh = b_rh[gcol], bzi = b_zi[gcol];
        const float bni = b_ni[gcol], bnh = b_nh[gcol];
        #pragma unroll
        for (int mi = 0; mi < 4; ++mi) {
            #pragma unroll
            for (int r4 = 0; r4 < 4; ++r4) {
                const int grow = row0 + wm * 64 + mi * 16 + quad * 4 + r4;
                const float g_ri = acc[0][mi][ni][r4];
                const float g_rh = acc[1][mi][ni][r4];
                const float g_zi = acc[2][mi][ni][r4];
                const float g_ni = acc[3][mi][ni][r4];
                const float g_nh = acc[4][mi][ni][r4];
                const float rh = g_rh + brh;                  // shared by r and z (reference bug kept)
                const float rr = 1.f / (1.f + __expf(-(g_ri + bri + rh)));
                const float zz = 1.f / (1.f + __expf(-(g_zi + bzi + rh)));
                const float nn = tanhf(g_ni + bni + rr * (g_nh + bnh));
                const float h  = hidden[(long long)grow * H + gcol];
                const float o  = (1.f - zz) * nn + zz * h;
                out[(long long)grow * H + gcol]      = o;
                out[BH + (long long)grow * H + gcol] = o;
            }
        }
    }
}

extern "C" void kernel_launch(void* const* d_in, const int* in_sizes, int n_in,
                              void* d_out, int out_size, void* d_ws, size_t ws_size,
                              hipStream_t stream) {
    const float* input  = (const float*)d_in[0];
    const float* hidden = (const float*)d_in[1];
    const float* W_ri = (const float*)d_in[2];
    const float* b_ri = (const float*)d_in[3];
    const float* W_rh = (const float*)d_in[4];
    const float* b_rh = (const float*)d_in[5];
    const float* W_zi = (const float*)d_in[6];
    const float* b_zi = (const float*)d_in[7];
    // d_in[8], d_in[9] = W_z_h, b_z_h: dead per the reference's bug (z uses r_h)
    const float* W_ni = (const float*)d_in[10];
    const float* b_ni = (const float*)d_in[11];
    const float* W_nh = (const float*)d_in[12];
    const float* b_nh = (const float*)d_in[13];
    float* out = (float*)d_out;
    (void)d_ws; (void)ws_size;

    dim3 grid(1024 / BN, 16384 / BM);  // (16, 128)
    gru_fused<<<grid, 256, 0, stream>>>(input, hidden,
                                        W_ri, W_rh, W_zi, W_ni, W_nh,
                                        b_ri, b_rh, b_zi, b_ni, b_nh, out);
}

// Round 6
// 488.799 us; speedup vs baseline: 8.5242x; 3.0268x over previous
//
#include <hip/hip_runtime.h>

// Round 8: best-component pairing. gru_fused = R1's verbatim best (270.6 us
// profiled: LDS double-buffer 2x36864, global_load_lds staging [zero staging
// regs - mandatory: 160-reg acc + 256-reg/wave cap at 2 waves/SIMD leaves no
// room for reg-staging, R5 spilled 1.78 GB scratch], counted vmcnt(9), XOR
// slot swizzle [conflicts=0], setprio, 4 waves 1x4M, no XCD swizzle).
// convert_bf16 = R0's one-shot version (18944 blocks, max MLP - grid-stride
// variant was +68 us). This pair was never benched together; it discriminates
// the two models of the ~500 us dur_us plateau (harness floor vs timed-run
// gru variance). Sum-model predicts ~430-470; floor-model ~496-505.

#define BM 128
#define BN 64
#define BK 32
#define TILE_BYTES 36864

typedef __attribute__((ext_vector_type(8))) short          bf16x8;
typedef __attribute__((ext_vector_type(8))) unsigned short u16x8;
typedef __attribute__((ext_vector_type(4))) float          f32x4;

__device__ __forceinline__ unsigned short f2bf(float f) {
    union { float f; unsigned u; } v; v.f = f;
    unsigned r = v.u + 0x7FFFu + ((v.u >> 16) & 1u);  // RNE
    return (unsigned short)(r >> 16);
}

// ---- Pass 1: fp32 -> bf16 conversion into ws (one vec8 per thread) ----
// ws layout (elements): [0) input 16777216 | [16777216) hidden 16777216 |
//                       [33554432 + g*1048576) W_g for g=0..4
// Total vec8 = 4,849,664 = 18944 blocks * 256.
__global__ __launch_bounds__(256) void convert_bf16(
    const float* __restrict__ in0, const float* __restrict__ in1,
    const float* __restrict__ w0, const float* __restrict__ w1,
    const float* __restrict__ w2, const float* __restrict__ w3,
    const float* __restrict__ w4, unsigned short* __restrict__ ws)
{
    const long long e = ((long long)blockIdx.x * 256 + threadIdx.x) * 8;
    const float* src;
    if (e < 16777216LL) {
        src = in0 + e;
    } else if (e < 33554432LL) {
        src = in1 + (e - 16777216LL);
    } else {
        const long long t = e - 33554432LL;
        const int g = (int)(t >> 20);
        const long long within = t & 1048575LL;
        const float* w = (g == 0) ? w0 : (g == 1) ? w1 : (g == 2) ? w2 : (g == 3) ? w3 : w4;
        src = w + within;
    }
    const float4 a = *reinterpret_cast<const float4*>(src);
    const float4 b = *reinterpret_cast<const float4*>(src + 4);
    u16x8 o;
    o[0] = f2bf(a.x); o[1] = f2bf(a.y); o[2] = f2bf(a.z); o[3] = f2bf(a.w);
    o[4] = f2bf(b.x); o[5] = f2bf(b.y); o[6] = f2bf(b.z); o[7] = f2bf(b.w);
    *reinterpret_cast<u16x8*>(ws + e) = o;
}

// ---- async 16B global->LDS ----
__device__ __forceinline__ void async16(const void* g, void* l) {
    __builtin_amdgcn_global_load_lds(
        (const __attribute__((address_space(1))) unsigned int*)g,
        (__attribute__((address_space(3))) unsigned int*)l, 16, 0, 0);
}

// compiler-level memory fence (no instruction) to bracket raw s_barrier so
// ds_reads cannot be hoisted above / sunk below it
#define CFENCE() asm volatile("" ::: "memory")

// ---- Pass 2: fused GRU, double-buffered + swizzled (R1 verbatim) ----
// Per-tile LDS image (bf16, linear dest as global_load_lds requires):
//   [0, 8192)       sIn  [128 rows][64 B]   (4 x 16B slots per row)
//   [8192, 16384)   sHid [128 rows][64 B]
//   [16384, 36864)  sW[5][64 rows][64 B]
// Slot swizzle: data for logical 16B slot c of row r is stored at physical
// slot c ^ ((r>>1)&3)  (applied on the GLOBAL source at staging; involution
// applied again on the read side). Measured SQ_LDS_BANK_CONFLICT = 0.
__global__ __launch_bounds__(256, 2) void gru_fused(
    const unsigned short* __restrict__ bf,   // ws: bf16 image
    const float* __restrict__ hidden,        // fp32, for epilogue z*h
    const float* __restrict__ b_ri, const float* __restrict__ b_rh,
    const float* __restrict__ b_zi, const float* __restrict__ b_ni,
    const float* __restrict__ b_nh,
    float* __restrict__ out)
{
    const int H = 1024, K = 1024;
    const int BH = 16384 * 1024;

    __shared__ __align__(16) unsigned char sBuf[2][TILE_BYTES];

    const int tid  = threadIdx.x;
    const int wave = tid >> 6;
    const int lane = tid & 63;
    const int quad = lane >> 4;
    const int l16  = lane & 15;
    const int sq   = quad ^ ((l16 >> 1) & 3);   // swizzled 16B slot for reads

    const int row0 = blockIdx.y * BM;
    const int col0 = blockIdx.x * BN;

    const unsigned short* inB  = bf;               // input  bf16 [16384][1024]
    const unsigned short* hidB = bf + 16777216;    // hidden bf16 [16384][1024]
    const unsigned short* wB   = bf + 33554432;    // W bf16 [5][1024][1024]

    // Per-slot global base pointers (k0=0, source slot pre-swizzled) + LDS offs.
    const unsigned short* srcbase[9];
    int ldsoff[9];
    #pragma unroll
    for (int j = 0; j < 9; ++j) {
        const int s = (j * 4 + wave) * 64 + lane;
        ldsoff[j] = s * 16;
        if (s < 512) {                       // input tile
            const int r = s >> 2;
            const int c = (s & 3) ^ ((r >> 1) & 3);
            srcbase[j] = inB + (long long)(row0 + r) * K + c * 8;
        } else if (s < 1024) {               // hidden tile
            const int r = (s - 512) >> 2;
            const int c = (s & 3) ^ ((r >> 1) & 3);
            srcbase[j] = hidB + (long long)(row0 + r) * K + c * 8;
        } else {                             // weight tiles
            const int t = s - 1024;
            const int g = t >> 8;
            const int tt = t & 255;
            const int n = tt >> 2;
            const int c = (tt & 3) ^ ((n >> 1) & 3);
            srcbase[j] = wB + (long long)g * 1048576 + (long long)(col0 + n) * K + c * 8;
        }
    }

    f32x4 acc[5][2][4];
    #pragma unroll
    for (int g = 0; g < 5; ++g)
        #pragma unroll
        for (int mi = 0; mi < 2; ++mi)
            #pragma unroll
            for (int ni = 0; ni < 4; ++ni)
                acc[g][mi][ni] = (f32x4){0.f, 0.f, 0.f, 0.f};

    unsigned char* b0 = &sBuf[0][0];
    unsigned char* b1 = &sBuf[1][0];

    auto stage = [&](int k0, unsigned char* dst) {
        #pragma unroll
        for (int j = 0; j < 9; ++j)
            async16(srcbase[j] + k0, dst + ldsoff[j]);
    };

    auto compute = [&](const unsigned char* sb) {
        bf16x8 aIn[2], aHid[2];
        #pragma unroll
        for (int mi = 0; mi < 2; ++mi) {
            const int r = wave * 32 + mi * 16 + l16;
            aIn [mi] = *reinterpret_cast<const bf16x8*>(sb + r * 64 + sq * 16);
            aHid[mi] = *reinterpret_cast<const bf16x8*>(sb + 8192 + r * 64 + sq * 16);
        }
        __builtin_amdgcn_s_setprio(1);
        #pragma unroll
        for (int g = 0; g < 5; ++g) {
            #pragma unroll
            for (int ni = 0; ni < 4; ++ni) {
                const int n = ni * 16 + l16;
                const bf16x8 b = *reinterpret_cast<const bf16x8*>(
                    sb + 16384 + g * 4096 + n * 64 + sq * 16);
                #pragma unroll
                for (int mi = 0; mi < 2; ++mi) {
                    const bf16x8 a = (g == 1 || g == 4) ? aHid[mi] : aIn[mi];
                    acc[g][mi][ni] = __builtin_amdgcn_mfma_f32_16x16x32_bf16(a, b, acc[g][mi][ni], 0, 0, 0);
                }
            }
        }
        __builtin_amdgcn_s_setprio(0);
    };

    // ---- pipelined K loop: 32 tiles, 1-deep prefetch, counted vmcnt ----
    // tile t lives in buf[t&1]. Per step: issue stage(t+1) -> wait OWN tile-t
    // loads (vmcnt(9): 9 newer in flight) -> barrier (=> ALL waves' tile-t
    // loads done) -> compute(t) -> barrier (buf[t] may be restaged at t+2).
    stage(0, b0);
    #pragma unroll 1
    for (int i = 0; i < 15; ++i) {
        const int k2 = i * 2 * BK;
        stage(k2 + BK, b1);
        asm volatile("s_waitcnt vmcnt(9)" ::: "memory");
        __builtin_amdgcn_s_barrier(); CFENCE();
        compute(b0); CFENCE();
        __builtin_amdgcn_s_barrier(); CFENCE();

        stage(k2 + 2 * BK, b0);
        asm volatile("s_waitcnt vmcnt(9)" ::: "memory");
        __builtin_amdgcn_s_barrier(); CFENCE();
        compute(b1); CFENCE();
        __builtin_amdgcn_s_barrier(); CFENCE();
    }
    // tiles 30 (in b0) and 31
    stage(31 * BK, b1);
    asm volatile("s_waitcnt vmcnt(9)" ::: "memory");
    __builtin_amdgcn_s_barrier(); CFENCE();
    compute(b0); CFENCE();
    __builtin_amdgcn_s_barrier(); CFENCE();
    asm volatile("s_waitcnt vmcnt(0)" ::: "memory");
    __builtin_amdgcn_s_barrier(); CFENCE();
    compute(b1);

    // Epilogue: C/D layout row = quad*4 + r4, col = l16 per 16x16 tile.
    #pragma unroll
    for (int ni = 0; ni < 4; ++ni) {
        const int gcol = col0 + ni * 16 + l16;
        const float bri = b_ri[gcol], brh = b_rh[gcol], bzi = b_zi[gcol];
        const float bni = b_ni[gcol], bnh = b_nh[gcol];
        #pragma unroll
        for (int mi = 0; mi < 2; ++mi) {
            #pragma unroll
            for (int r4 = 0; r4 < 4; ++r4) {
                const int grow = row0 + wave * 32 + mi * 16 + quad * 4 + r4;
                const float g_ri = acc[0][mi][ni][r4];
                const float g_rh = acc[1][mi][ni][r4];
                const float g_zi = acc[2][mi][ni][r4];
                const float g_ni = acc[3][mi][ni][r4];
                const float g_nh = acc[4][mi][ni][r4];
                const float rh = g_rh + brh;                  // shared by r and z (reference bug kept)
                const float rr = 1.f / (1.f + __expf(-(g_ri + bri + rh)));
                const float zz = 1.f / (1.f + __expf(-(g_zi + bzi + rh)));
                const float nn = tanhf(g_ni + bni + rr * (g_nh + bnh));
                const float h  = hidden[(long long)grow * H + gcol];
                const float o  = (1.f - zz) * nn + zz * h;
                out[(long long)grow * H + gcol]      = o;
                out[BH + (long long)grow * H + gcol] = o;
            }
        }
    }
}

extern "C" void kernel_launch(void* const* d_in, const int* in_sizes, int n_in,
                              void* d_out, int out_size, void* d_ws, size_t ws_size,
                              hipStream_t stream) {
    const float* input  = (const float*)d_in[0];
    const float* hidden = (const float*)d_in[1];
    const float* W_ri = (const float*)d_in[2];
    const float* b_ri = (const float*)d_in[3];
    const float* W_rh = (const float*)d_in[4];
    const float* b_rh = (const float*)d_in[5];
    const float* W_zi = (const float*)d_in[6];
    const float* b_zi = (const float*)d_in[7];
    // d_in[8], d_in[9] = W_z_h, b_z_h: dead per the reference's bug (z uses r_h)
    const float* W_ni = (const float*)d_in[10];
    const float* b_ni = (const float*)d_in[11];
    const float* W_nh = (const float*)d_in[12];
    const float* b_nh = (const float*)d_in[13];
    float* out = (float*)d_out;
    unsigned short* ws = (unsigned short*)d_ws;

    // gate order in ws: 0=r_i 1=r_h 2=z_i 3=n_i 4=n_h
    convert_bf16<<<18944, 256, 0, stream>>>(input, hidden, W_ri, W_rh, W_zi, W_ni, W_nh, ws);

    dim3 grid(1024 / BN, 16384 / BM);  // (16, 128)
    gru_fused<<<grid, 256, 0, stream>>>(ws, hidden, b_ri, b_rh, b_zi, b_ni, b_nh, out);
}